// Round 11
// baseline (186.498 us; speedup 1.0000x reference)
//
#include <hip/hip_runtime.h>
#include <cstdint>

typedef float  f32x16 __attribute__((ext_vector_type(16)));
typedef short  s16x8  __attribute__((ext_vector_type(8)));

__device__ __forceinline__ unsigned short f2bf(float f){
  unsigned int u = __float_as_uint(f);
  return (unsigned short)((u + 0x7FFFu + ((u >> 16) & 1u)) >> 16);   // RNE
}

// g_Wt[tap][o][ci] bf16, tap = kh*3+kw : W[o][ci][kh][kw]
__device__ alignas(16) unsigned short g_Wt[9*64*64];

__global__ void wt_kernel(const float* __restrict__ w){
  int t = blockIdx.x*256 + threadIdx.x;          // 36864 total
  if (t >= 9*64*64) return;
  int ci = t & 63, o = (t >> 6) & 63, tap = t >> 12;
  int kh = tap/3, kw = tap%3;
  g_Wt[t] = f2bf(w[((o*64 + ci)*3 + kh)*3 + kw]);
}

// dslab: [34 cols][2 rows][64 ci] bf16, 256B col-stride; R8-verbatim layout:
// (full byte offset) ^ ((c&15)<<4)  [measured 0 conflicts in R4/R8/R9]
#define DSLABU 8704

__global__ __launch_bounds__(256) void conv_main(const float* __restrict__ x,
                                                 const float* __restrict__ bias,
                                                 float* __restrict__ out){
  __shared__ alignas(16) char smem[2*DSLABU];    // 17408 B -> LDS allows 9 blocks/CU
  // grid 8128 = 8 XCDs x 1016; XCD k owns batch k; within: 8 col-strips per
  // row-pair consecutive -> staged rows are XCD-L2-hot across strips & ypairs.
  const int id   = blockIdx.x;
  const int wgid = (id & 7)*1016 + (id >> 3);
  const int b    = wgid / 1016;
  const int rem  = wgid - b*1016;
  const int by = rem >> 3, strip = rem & 7;
  const int y0 = by*2, n0 = strip*32;            // outputs: rows y0,y0+1; cols n0..n0+31

  const int tid = threadIdx.x, lane = tid & 63, wv = tid >> 6;
  const int wrow = wv & 1, wct = wv >> 1;        // wave = row x Cout-half
  const int l31 = lane & 31, hh = lane >> 5;
  const int cp = tid & 31, q2 = tid >> 5;        // staging: ci-pair, col-quad
  const float* xb = x + (size_t)b*64*65536;

  // ---- stage 4 input rows (y0..y0+3) into 2 dslabs; load-all-then-cvt ----
  #pragma unroll
  for (int d = 0; d < 2; ++d){
    const int rr = y0 + 2*d;                     // rr+1 <= 255 (by <= 126)
    char* slab = smem + d*DSLABU;

    float4 v0[4];
    {                                            // task A: q = q2 (cols 4q..4q+3)
      int cg = n0 + q2*4;                        // <= 252, in range
      const float* p = xb + (size_t)(2*cp)*65536 + (size_t)rr*256 + cg;
      v0[0] = *(const float4*)p;
      v0[1] = *(const float4*)(p + 65536);
      v0[2] = *(const float4*)(p + 256);
      v0[3] = *(const float4*)(p + 65536 + 256);
    }
    float4 v1[4];
    const bool t1 = (q2 == 0);                   // task B: cols 32..35 (use 32,33)
    if (t1){
      int cg = n0 + 32; if (cg > 252) cg = 252;  // clamp feeds only discarded n>=254
      const float* p = xb + (size_t)(2*cp)*65536 + (size_t)rr*256 + cg;
      v1[0] = *(const float4*)p;
      v1[1] = *(const float4*)(p + 65536);
      v1[2] = *(const float4*)(p + 256);
      v1[3] = *(const float4*)(p + 65536 + 256);
    }

    {
      const int c0 = q2*4;
      const float* a00 = (const float*)&v0[0];
      const float* a01 = (const float*)&v0[1];
      const float* a10 = (const float*)&v0[2];
      const float* a11 = (const float*)&v0[3];
      #pragma unroll
      for (int j = 0; j < 4; ++j){
        int c = c0 + j;                          // 0..31
        unsigned pk0 = (unsigned)f2bf(a00[j]) | ((unsigned)f2bf(a01[j]) << 16);
        unsigned pk1 = (unsigned)f2bf(a10[j]) | ((unsigned)f2bf(a11[j]) << 16);
        int swz = (c & 15) << 4;
        int base = c*256 + cp*4;
        *(unsigned*)(slab + ((base      ) ^ swz)) = pk0;   // row rr
        *(unsigned*)(slab + ((base + 128) ^ swz)) = pk1;   // row rr+1
      }
    }
    if (t1){
      const float* a00 = (const float*)&v1[0];
      const float* a01 = (const float*)&v1[1];
      const float* a10 = (const float*)&v1[2];
      const float* a11 = (const float*)&v1[3];
      #pragma unroll
      for (int j = 0; j < 2; ++j){
        int c = 32 + j;                          // cols 32,33
        unsigned pk0 = (unsigned)f2bf(a00[j]) | ((unsigned)f2bf(a01[j]) << 16);
        unsigned pk1 = (unsigned)f2bf(a10[j]) | ((unsigned)f2bf(a11[j]) << 16);
        int swz = (c & 15) << 4;
        int base = c*256 + cp*4;
        *(unsigned*)(slab + ((base      ) ^ swz)) = pk0;
        *(unsigned*)(slab + ((base + 128) ^ swz)) = pk1;
      }
    }
  }
  __syncthreads();

  // ---- compute: wave = row (y0+wrow) x Cout (wct*32..+31) x cols n0..n0+31 ----
  f32x16 acc;
  #pragma unroll
  for (int i = 0; i < 16; ++i) acc[i] = 0.f;

  #pragma unroll
  for (int kw = 0; kw < 3; ++kw){
    const int c   = l31 + kw;                    // staged col 0..33
    const int swz = (c & 15) << 4;
    const int cb  = c*256 + hh*16;
    #pragma unroll
    for (int c16 = 0; c16 < 4; ++c16){
      #pragma unroll
      for (int kh = 0; kh < 3; ++kh){
        const int r   = wrow + kh;               // staged row 0..3
        const int off = cb + c16*32 + (r & 1)*128;
        s16x8 bf = *(const s16x8*)(smem + (r >> 1)*DSLABU + (off ^ swz));
        s16x8 af = *(const s16x8*)(
            &g_Wt[((kh*3 + kw)*64 + wct*32 + l31)*64 + c16*16 + hh*8]);
        acc = __builtin_amdgcn_mfma_f32_32x32x16_bf16(af, bf, acc, 0, 0, 0);
      }
    }
  }

  // ---- store (C/D map: col=l31 -> n; row = 4*hh + (reg&3)+8*(reg>>2) -> o) ----
  const int nl = n0 + l31;
  const int y  = y0 + wrow;
  const int ob = wct*32 + 4*hh;
  if (nl < 254){
    size_t rb = (((size_t)b*64 + ob)*254 + y)*254 + nl;
    #pragma unroll
    for (int reg = 0; reg < 16; ++reg){
      int od = (reg & 3) + 8*(reg >> 2);
      out[rb + (size_t)od*64516] = acc[reg] + bias[ob + od];
    }
  }
}

extern "C" void kernel_launch(void* const* d_in, const int* in_sizes, int n_in,
                              void* d_out, int out_size, void* d_ws, size_t ws_size,
                              hipStream_t stream) {
  const float* x    = (const float*)d_in[0];
  const float* wgt  = (const float*)d_in[1];
  const float* bias = (const float*)d_in[2];
  float* out = (float*)d_out;

  wt_kernel<<<144, 256, 0, stream>>>(wgt);
  conv_main<<<8128, 256, 0, stream>>>(x, bias, out);
}